// Round 13
// baseline (1901.953 us; speedup 1.0000x reference)
//
#include <hip/hip_runtime.h>
#include <hip/hip_bf16.h>
#include <stdint.h>

#define T_TOK 1024
#define H_DIM 2048
#define NEXP 8
#define IED 1408
#define ISD 5632

typedef __attribute__((ext_vector_type(8))) short s16x8;
typedef __attribute__((ext_vector_type(8))) unsigned short u16x8;
typedef __attribute__((ext_vector_type(4))) float f32x4;

// 4-chunk swizzle, bank-quad balanced over 16-row period
#define SWZ(r) (((r) ^ ((r) >> 2)) & 3)

// HW bf16 convert (RNE, lowers to v_cvt_pk_bf16_f32)
__device__ __forceinline__ unsigned short f2bf(float f) {
  union { __hip_bfloat16 b; unsigned short u; } v;
  v.b = __float2bfloat16(f);
  return v.u;
}

__device__ __forceinline__ void gload16(const void* g, void* l) {
  __builtin_amdgcn_global_load_lds(
      (const __attribute__((address_space(1))) unsigned int*)g,
      (__attribute__((address_space(3))) unsigned int*)l, 16, 0, 0);
}

// ---------------- router + x->bf16 convert (fused) ----------------
extern "C" __global__ void __launch_bounds__(256) k_router(
    const float* __restrict__ x, const float* __restrict__ wg,
    const float* __restrict__ wsg, unsigned short* __restrict__ xb,
    int* __restrict__ counts, int* __restrict__ tlist,
    float* __restrict__ wlist, float* __restrict__ gate_sig) {
  const int tid = threadIdx.x;
  const int bb = blockIdx.x;
#pragma unroll
  for (int it = 0; it < 8; it++) {
    int i = bb * 8192 + it * 1024 + tid * 4;
    float4 v = *(const float4*)(x + i);
    ushort4 o;
    o.x = f2bf(v.x); o.y = f2bf(v.y); o.z = f2bf(v.z); o.w = f2bf(v.w);
    *(ushort4*)(xb + i) = o;
  }
  const int lane = tid & 63;
  const int t = bb * 4 + (tid >> 6);
  const float* xr = x + (size_t)t * H_DIM;
  float acc[8];
#pragma unroll
  for (int e = 0; e < 8; e++) acc[e] = 0.f;
  float sg = 0.f;
  for (int h = lane; h < H_DIM; h += 64) {
    float xv = xr[h];
    float4 w0 = *(const float4*)(wg + h * 8);
    float4 w1 = *(const float4*)(wg + h * 8 + 4);
    acc[0] += xv * w0.x; acc[1] += xv * w0.y; acc[2] += xv * w0.z; acc[3] += xv * w0.w;
    acc[4] += xv * w1.x; acc[5] += xv * w1.y; acc[6] += xv * w1.z; acc[7] += xv * w1.w;
    sg += xv * wsg[h];
  }
#pragma unroll
  for (int d = 32; d >= 1; d >>= 1) {
#pragma unroll
    for (int e = 0; e < 8; e++) acc[e] += __shfl_xor(acc[e], d, 64);
    sg += __shfl_xor(sg, d, 64);
  }
  if (lane == 0) {
    float m = acc[0];
#pragma unroll
    for (int e = 1; e < 8; e++) m = fmaxf(m, acc[e]);
    float p[8], s = 0.f;
#pragma unroll
    for (int e = 0; e < 8; e++) { p[e] = __expf(acc[e] - m); s += p[e]; }
    float inv = 1.f / s;
    bool used[8];
#pragma unroll
    for (int e = 0; e < 8; e++) used[e] = false;
    for (int j = 0; j < 4; j++) {
      int be = 0; float bv = -1e30f;
#pragma unroll
      for (int e = 0; e < 8; e++)
        if (!used[e] && acc[e] > bv) { bv = acc[e]; be = e; }
      used[be] = true;
      int slot = atomicAdd(counts + be, 1);
      tlist[be * T_TOK + slot] = t;
      wlist[be * T_TOK + slot] = p[be] * inv;
    }
    gate_sig[t] = 1.f / (1.f + __expf(-sg));
  }
}

// ---------------- staging macros (256 threads) ----------------
// A via DMA (gu only): 2 gload16/thread, r6-proven geometry.
#define ISSUE_AD(kk, AOFF)                                                \
  do {                                                                    \
    _Pragma("unroll") for (int q = 0; q < 2; q++)                         \
        gload16(asrc[q] + (kk), adst[q] + (AOFF));                        \
    __builtin_amdgcn_sched_barrier(0);                                    \
  } while (0)

// B: 16 dword loads/thread. col bnn = tid&127, k = kk + bc*16 + j.
#define ISSUE_B(kk)                                                       \
  do {                                                                    \
    _Pragma("unroll") for (int j = 0; j < 16; j++)                        \
        RB[j] = Bh[(size_t)((kk) + bc * 16 + j) * (size_t)ldb];           \
    __builtin_amdgcn_sched_barrier(0);                                    \
  } while (0)

// convert 16 fp32 -> two b128 LDS writes at chunks (bc*2+t)^SWZ(bnn)
#define CVTB(BOFF)                                                        \
  do {                                                                    \
    _Pragma("unroll") for (int t = 0; t < 2; t++) {                       \
      u16x8 pk;                                                           \
      _Pragma("unroll") for (int j = 0; j < 8; j++)                       \
          pk[j] = f2bf(RB[t * 8 + j]);                                    \
      *(u16x8*)(bwr[t] + (BOFF)) = pk;                                    \
    }                                                                     \
  } while (0)

// A-frags from packed global (down only): 4 coalesced b128 loads/wave.
#define ISSUE_AF(SET, cc)                                                 \
  do {                                                                    \
    _Pragma("unroll") for (int m = 0; m < 4; m++)                         \
        SET[m] = *(const s16x8*)(apkb + ((size_t)m * CKa + (cc)) * 512);  \
    __builtin_amdgcn_sched_barrier(0);                                    \
  } while (0)

// ---------------- fused MFMA GEMM pair, 4 waves x 64x64 tiles ----------------
// DOWN=0: shared-gu (0..703) + expert-gu (704..2111), nt=64, A via LDS DMA
// DOWN=1: shared-down splitK4 (0..511) + expert-down (512..1535), nt=44,
//         A-frags direct from packed activations (no A LDS)
template <int DOWN>
__global__ void k_mm(
    const unsigned short* __restrict__ A_sh, const unsigned short* __restrict__ A_ex,
    const float* __restrict__ B_sh, const float* __restrict__ B_ex,
    unsigned short* __restrict__ act_sh, unsigned short* __restrict__ act_ex,
    float* __restrict__ out,
    const int* __restrict__ counts, const int* __restrict__ tlist,
    const float* __restrict__ wlist, const float* __restrict__ gate_sig) {
  const int tid = threadIdx.x;
  const int lane = tid & 63;
  const int wid = tid >> 6;
  const int wm = wid >> 1, wn = wid & 1;  // 4 waves: 2x2 of 64x64

  constexpr int SHBLK = DOWN ? 512 : 704;
  constexpr int nt = DOWN ? 44 : 64;
  const int b0 = blockIdx.x;
  const bool ex = b0 >= SHBLK;
  const int b = ex ? b0 - SHBLK : b0;
  const int xcd = b & 7;
  const int j = b >> 3;
  const int mtile = j & 7;
  int e = 0, ntile = 0, z = 0;
  if constexpr (!DOWN) {
    if (!ex) ntile = xcd * 11 + (j >> 3);
    else { e = xcd; ntile = j >> 3; }          // e = XCD: A/B panels L2-resident
  } else {
    if (!ex) { int p = xcd * 8 + (j >> 3); ntile = p >> 2; z = p & 3; }
    else { e = xcd; ntile = j >> 3; }
  }

  int lda = 0, ldb, IK = 0, kbeg = 0, count = T_TOK, CKa = 0;
  const unsigned short* A = nullptr;      // gu: linear bf16 rows
  const unsigned short* Apk = nullptr;    // down: packed frags
  const float* Bb0; const float* Bb1;
  const int* tlA = nullptr;
  const int* tlO = nullptr;
  const float* wl = nullptr;
  unsigned short* actout = nullptr;

  if constexpr (!DOWN) {
    lda = H_DIM;
    if (!ex) {
      ldb = 2 * ISD; IK = ISD; A = A_sh; actout = act_sh;
      Bb0 = B_sh + ntile * 64; Bb1 = B_sh + ISD + ntile * 64;
    } else {
      count = counts[e];
      if (mtile * 128 >= count) return;
      ldb = 2 * IED; IK = IED; A = A_sh;
      const float* Bw = B_ex + (size_t)e * H_DIM * (2 * IED);
      Bb0 = Bw + ntile * 64; Bb1 = Bw + IED + ntile * 64;
      tlA = tlist + e * T_TOK; wl = wlist + e * T_TOK;
      actout = act_ex + (size_t)e * T_TOK * IED;
    }
  } else {
    ldb = H_DIM;
    if (!ex) {
      kbeg = z * 1408; Apk = A_sh; CKa = ISD >> 5;   // 176
      Bb0 = B_sh + ntile * 128; Bb1 = Bb0;
    } else {
      count = counts[e];
      if (mtile * 128 >= count) return;
      Apk = A_ex + (size_t)e * T_TOK * IED; CKa = IED >> 5;  // 44
      Bb0 = B_ex + (size_t)e * IED * H_DIM + ntile * 128; Bb1 = Bb0;
      tlO = tlist + e * T_TOK;
    }
  }

  __shared__ unsigned short a_lds[DOWN ? 64 : 2 * 4096];
  __shared__ unsigned short b_lds[2 * 4096];

  // gu A staging (DMA): row = wid*32 + q*16 + (lane>>2), chunkpos = lane&3.
  const unsigned short* asrc[2];
  unsigned short* adst[2];
  if constexpr (!DOWN) {
#pragma unroll
    for (int q = 0; q < 2; q++) {
      int row = wid * 32 + q * 16 + (lane >> 2);
      int rowg = mtile * 128 + row;
      int arow = rowg;
      if (tlA) arow = tlA[rowg];  // padding slots hold 0 (memset)
      asrc[q] = A + (size_t)arow * lda + (((lane & 3) ^ SWZ(row)) * 8);
      adst[q] = &a_lds[(wid * 32 + q * 16) * 32];
    }
  }

  // down A-frag base: g0 = mtile*8 + wm*4; addr(m,c) = ((g0+m)*CKa + c)*512 + lane*8
  const unsigned short* apkb = nullptr;
  if constexpr (DOWN)
    apkb = Apk + (size_t)(mtile * 8 + wm * 4) * CKa * 512 + lane * 8;

  // B staging: col bnn = tid&127, k-half bc = tid>>7.
  const int bnn = tid & 127;
  const int bc = tid >> 7;
  const float* Bh;
  if constexpr (!DOWN) Bh = (bnn < 64) ? (Bb0 + bnn) : (Bb1 + (bnn - 64));
  else Bh = Bb0 + bnn;
  unsigned short* bwr[2];
#pragma unroll
  for (int t = 0; t < 2; t++)
    bwr[t] = &b_lds[bnn * 32 + (((bc * 2 + t) ^ SWZ(bnn)) * 8)];

  const f32x4 fzero = {0.f, 0.f, 0.f, 0.f};
  f32x4 acc[4][4];
#pragma unroll
  for (int m = 0; m < 4; m++)
#pragma unroll
    for (int n = 0; n < 4; n++) acc[m][n] = fzero;

  float RB[16];

  if constexpr (!DOWN) {
    // ---------------- gu: A via LDS DMA, r10-proven ledger ----------------
    ISSUE_AD(kbeg, 0);            // A(0) [2 DMA]
    ISSUE_B(kbeg);                // B(0) [16]
    ISSUE_AD(kbeg + 32, 4096);    // A(1) [2]
    CVTB(0);                      // waits B(0) -> drains A(0); A(1) stays
    ISSUE_B(kbeg + 32);           // B(1) [16]
    __builtin_amdgcn_sched_barrier(0);
    asm volatile("s_waitcnt lgkmcnt(0)" ::: "memory");
    __builtin_amdgcn_s_barrier();
    __builtin_amdgcn_sched_barrier(0);
    // pending: A(1)[2] + B(1)[16]
    for (int u = 0; u < nt; ++u) {
      const int cur = (u & 1) * 4096;
      const int nxt = cur ^ 4096;
      const int k0 = kbeg + u * 32;
      const bool haveN1 = (u + 1 < nt);
      const bool haveN2 = (u + 2 < nt);
      if (haveN1) {
        ISSUE_AD(k0 + 32, nxt);
        CVTB(nxt);                    // B(u+1) regs -> nxt (compiler-counted)
        if (haveN2) ISSUE_B(k0 + 64);
      }
      {  // COMPUTE from LDS A + LDS B
        const unsigned short* ab = a_lds + cur;
        const unsigned short* bb2 = b_lds + cur;
        __builtin_amdgcn_s_setprio(1);
        const int kc = lane >> 4;
        s16x8 am[4];
#pragma unroll
        for (int m = 0; m < 4; m++) {
          int r = wm * 64 + m * 16 + (lane & 15);
          am[m] = *(const s16x8*)&ab[r * 32 + ((kc ^ SWZ(r)) * 8)];
        }
#pragma unroll
        for (int nf = 0; nf < 4; nf++) {
          int rb_ = (nf < 2) ? (wn * 32 + nf * 16) : (64 + wn * 32 + (nf - 2) * 16);
          rb_ += (lane & 15);
          s16x8 bf = *(const s16x8*)&bb2[rb_ * 32 + ((kc ^ SWZ(rb_)) * 8)];
#pragma unroll
          for (int m = 0; m < 4; m++)
            acc[m][nf] = __builtin_amdgcn_mfma_f32_16x16x32_bf16(am[m], bf, acc[m][nf], 0, 0, 0);
        }
        __builtin_amdgcn_s_setprio(0);
      }
      if (haveN1) {
        __builtin_amdgcn_sched_barrier(0);
        if (haveN2)
          asm volatile("s_waitcnt vmcnt(16)" ::: "memory");  // drain A(u+1); keep B(u+2)
        else
          asm volatile("s_waitcnt vmcnt(0)" ::: "memory");
        asm volatile("s_waitcnt lgkmcnt(0)" ::: "memory");
        __builtin_amdgcn_s_barrier();
        __builtin_amdgcn_sched_barrier(0);
      }
    }
    // ---- epilogue: silu(g)*u*rsc -> PACKED activation layout ----
#pragma unroll
    for (int m = 0; m < 4; m++) {
      const int g = mtile * 8 + wm * 4 + m;
#pragma unroll
      for (int i = 0; i < 4; i++) {
        int rowslot = mtile * 128 + wm * 64 + m * 16 + (lane >> 4) * 4 + i;
        float rsc = 1.f;
        if (wl) rsc = wl[rowslot];  // padding slots: 0.0 (memset)
        int l2b = (lane >> 4) * 4 + i + ((lane >> 3) & 1) * 16;
#pragma unroll
        for (int p = 0; p < 2; p++) {
          float gv = acc[m][p][i];
          float uv = acc[m][p + 2][i];
          float sv = gv / (1.f + __expf(-gv)) * uv * rsc;
          size_t addr = ((size_t)(g * (IK >> 5) + ntile * 2 + wn) * 64 + (l2b + p * 32)) * 8 + (lane & 7);
          actout[addr] = f2bf(sv);
        }
      }
    }
  } else {
    // ---------------- down: A-frags direct from packed global ----------------
    s16x8 AF0[4], AF1[4];
    const int c0 = kbeg >> 5;
    ISSUE_AF(AF0, c0);            // AF(0) [4 reg loads]
    ISSUE_B(kbeg);                // B(0) [16]
    CVTB(0);                      // waits B(0)
    ISSUE_B(kbeg + 32);           // B(1) [16]
    __builtin_amdgcn_sched_barrier(0);
    asm volatile("s_waitcnt lgkmcnt(0)" ::: "memory");
    __builtin_amdgcn_s_barrier();
    __builtin_amdgcn_sched_barrier(0);

#define DN_STEP(UU, AFC, AFN)                                             \
    do {                                                                  \
      const int u_ = (UU);                                                \
      const int cur_ = (u_ & 1) * 4096;                                   \
      const bool h1 = (u_ + 1 < nt), h2 = (u_ + 2 < nt);                  \
      if (h1) {                                                           \
        ISSUE_AF(AFN, c0 + u_ + 1);                                       \
        CVTB(cur_ ^ 4096);                                                \
        if (h2) ISSUE_B(kbeg + u_ * 32 + 64);                             \
      }                                                                   \
      {                                                                   \
        const unsigned short* bb2 = b_lds + cur_;                         \
        __builtin_amdgcn_s_setprio(1);                                    \
        const int kc = lane >> 4;                                         \
        _Pragma("unroll") for (int nf = 0; nf < 4; nf++) {                \
          int rb_ = wn * 64 + nf * 16 + (lane & 15);                      \
          s16x8 bf = *(const s16x8*)&bb2[rb_ * 32 + ((kc ^ SWZ(rb_)) * 8)]; \
          _Pragma("unroll") for (int m = 0; m < 4; m++)                   \
              acc[m][nf] = __builtin_amdgcn_mfma_f32_16x16x32_bf16(       \
                  AFC[m], bf, acc[m][nf], 0, 0, 0);                       \
        }                                                                 \
        __builtin_amdgcn_s_setprio(0);                                    \
      }                                                                   \
      if (h1) {                                                           \
        __builtin_amdgcn_sched_barrier(0);                                \
        asm volatile("s_waitcnt lgkmcnt(0)" ::: "memory");                \
        __builtin_amdgcn_s_barrier();                                     \
        __builtin_amdgcn_sched_barrier(0);                                \
      }                                                                   \
    } while (0)

    for (int u = 0; u < nt; u += 2) {
      DN_STEP(u, AF0, AF1);
      DN_STEP(u + 1, AF1, AF0);
    }
#undef DN_STEP

    // ---- epilogue: scatter atomicAdd ----
#pragma unroll
    for (int m = 0; m < 4; m++) {
#pragma unroll
      for (int i = 0; i < 4; i++) {
        int rowslot = mtile * 128 + wm * 64 + m * 16 + (lane >> 4) * 4 + i;
        int token = rowslot;
        if (tlO) token = tlO[rowslot];  // padding: token 0, acc==0
        float sc = ex ? 1.f : gate_sig[token];
        float* orow = out + (size_t)token * H_DIM + ntile * 128 + wn * 64 + (lane & 15);
#pragma unroll
        for (int nf = 0; nf < 4; nf++)
          atomicAdd(orow + nf * 16, acc[m][nf][i] * sc);
      }
    }
  }
}

extern "C" void kernel_launch(void* const* d_in, const int* in_sizes, int n_in,
                              void* d_out, int out_size, void* d_ws, size_t ws_size,
                              hipStream_t stream) {
  (void)in_sizes; (void)n_in; (void)out_size; (void)ws_size;
  const float* x    = (const float*)d_in[0];
  const float* wg   = (const float*)d_in[1];
  const float* wsg  = (const float*)d_in[2];
  const float* wsgu = (const float*)d_in[3];
  const float* wsd  = (const float*)d_in[4];
  const float* wegu = (const float*)d_in[5];
  const float* wed  = (const float*)d_in[6];
  float* out = (float*)d_out;

  char* ws = (char*)d_ws;
  unsigned short* xb   = (unsigned short*)ws;                                   // 4 MB
  unsigned short* acts = (unsigned short*)(ws + (4u << 20));                    // packed, T*ISD bf16
  unsigned short* acte = (unsigned short*)(ws + (4u << 20) + 11534336u);        // packed, E*T*IED bf16
  char* ctrl = ws + (4u << 20) + 11534336u + 23068672u;
  int* counts    = (int*)ctrl;
  int* tlist     = (int*)(ctrl + 256);
  float* wlist   = (float*)(ctrl + 256 + 32768);
  float* gate_sig = (float*)(ctrl + 256 + 65536);

  hipMemsetAsync(d_out, 0, (size_t)T_TOK * H_DIM * 4, stream);
  hipMemsetAsync(ctrl, 0, 256 + 65536, stream);

  k_router<<<dim3(256), dim3(256), 0, stream>>>(x, wg, wsg, xb, counts, tlist, wlist, gate_sig);
  k_mm<0><<<dim3(2112), dim3(256), 0, stream>>>(xb, xb, wsgu, wegu, acts, acte, nullptr,
                                                counts, tlist, wlist, gate_sig);
  k_mm<1><<<dim3(1536), dim3(256), 0, stream>>>(acts, acte, wsd, wed, nullptr, nullptr, out,
                                                counts, tlist, wlist, gate_sig);
}

// Round 14
// 617.162 us; speedup vs baseline: 3.0818x; 3.0818x over previous
//
#include <hip/hip_runtime.h>
#include <hip/hip_bf16.h>
#include <stdint.h>

#define T_TOK 1024
#define H_DIM 2048
#define NEXP 8
#define IED 1408
#define ISD 5632

typedef __attribute__((ext_vector_type(8))) short s16x8;
typedef __attribute__((ext_vector_type(8))) unsigned short u16x8;
typedef __attribute__((ext_vector_type(4))) float f32x4;

// 4-chunk swizzle, bank-quad balanced over 16-row period
#define SWZ(r) (((r) ^ ((r) >> 2)) & 3)

// HW bf16 convert (RNE, lowers to v_cvt_pk_bf16_f32)
__device__ __forceinline__ unsigned short f2bf(float f) {
  union { __hip_bfloat16 b; unsigned short u; } v;
  v.b = __float2bfloat16(f);
  return v.u;
}

__device__ __forceinline__ void gload16(const void* g, void* l) {
  __builtin_amdgcn_global_load_lds(
      (const __attribute__((address_space(1))) unsigned int*)g,
      (__attribute__((address_space(3))) unsigned int*)l, 16, 0, 0);
}

// ---------------- router + x->bf16 convert (fused) ----------------
extern "C" __global__ void __launch_bounds__(256) k_router(
    const float* __restrict__ x, const float* __restrict__ wg,
    const float* __restrict__ wsg, unsigned short* __restrict__ xb,
    int* __restrict__ counts, int* __restrict__ tlist,
    float* __restrict__ wlist, float* __restrict__ gate_sig) {
  const int tid = threadIdx.x;
  const int bb = blockIdx.x;
#pragma unroll
  for (int it = 0; it < 8; it++) {
    int i = bb * 8192 + it * 1024 + tid * 4;
    float4 v = *(const float4*)(x + i);
    ushort4 o;
    o.x = f2bf(v.x); o.y = f2bf(v.y); o.z = f2bf(v.z); o.w = f2bf(v.w);
    *(ushort4*)(xb + i) = o;
  }
  const int lane = tid & 63;
  const int t = bb * 4 + (tid >> 6);
  const float* xr = x + (size_t)t * H_DIM;
  float acc[8];
#pragma unroll
  for (int e = 0; e < 8; e++) acc[e] = 0.f;
  float sg = 0.f;
  for (int h = lane; h < H_DIM; h += 64) {
    float xv = xr[h];
    float4 w0 = *(const float4*)(wg + h * 8);
    float4 w1 = *(const float4*)(wg + h * 8 + 4);
    acc[0] += xv * w0.x; acc[1] += xv * w0.y; acc[2] += xv * w0.z; acc[3] += xv * w0.w;
    acc[4] += xv * w1.x; acc[5] += xv * w1.y; acc[6] += xv * w1.z; acc[7] += xv * w1.w;
    sg += xv * wsg[h];
  }
#pragma unroll
  for (int d = 32; d >= 1; d >>= 1) {
#pragma unroll
    for (int e = 0; e < 8; e++) acc[e] += __shfl_xor(acc[e], d, 64);
    sg += __shfl_xor(sg, d, 64);
  }
  if (lane == 0) {
    float m = acc[0];
#pragma unroll
    for (int e = 1; e < 8; e++) m = fmaxf(m, acc[e]);
    float p[8], s = 0.f;
#pragma unroll
    for (int e = 0; e < 8; e++) { p[e] = __expf(acc[e] - m); s += p[e]; }
    float inv = 1.f / s;
    bool used[8];
#pragma unroll
    for (int e = 0; e < 8; e++) used[e] = false;
    for (int j = 0; j < 4; j++) {
      int be = 0; float bv = -1e30f;
#pragma unroll
      for (int e = 0; e < 8; e++)
        if (!used[e] && acc[e] > bv) { bv = acc[e]; be = e; }
      used[be] = true;
      int slot = atomicAdd(counts + be, 1);
      tlist[be * T_TOK + slot] = t;
      wlist[be * T_TOK + slot] = p[be] * inv;
    }
    gate_sig[t] = 1.f / (1.f + __expf(-sg));
  }
}

// ---------------- staging macros (256 threads) ----------------
// A via DMA (gu only): 2 gload16/thread.
#define ISSUE_AD(kk, AOFF)                                                \
  do {                                                                    \
    _Pragma("unroll") for (int q = 0; q < 2; q++)                         \
        gload16(asrc[q] + (kk), adst[q] + (AOFF));                        \
    __builtin_amdgcn_sched_barrier(0);                                    \
  } while (0)

// B: 16 dword loads/thread. col bnn = tid&127, k = kk + bc*16 + j.
#define ISSUE_B(kk)                                                       \
  do {                                                                    \
    _Pragma("unroll") for (int j = 0; j < 16; j++)                        \
        RB[j] = Bh[(size_t)((kk) + bc * 16 + j) * (size_t)ldb];           \
    __builtin_amdgcn_sched_barrier(0);                                    \
  } while (0)

// convert 16 fp32 -> two b128 LDS writes at chunks (bc*2+t)^SWZ(bnn)
#define CVTB(BOFF)                                                        \
  do {                                                                    \
    _Pragma("unroll") for (int t = 0; t < 2; t++) {                       \
      u16x8 pk;                                                           \
      _Pragma("unroll") for (int j = 0; j < 8; j++)                       \
          pk[j] = f2bf(RB[t * 8 + j]);                                    \
      *(u16x8*)(bwr[t] + (BOFF)) = pk;                                    \
    }                                                                     \
  } while (0)

// A-frags from packed global (down only): 4 coalesced b128 loads/wave.
#define ISSUE_AF(SET, cc)                                                 \
  do {                                                                    \
    _Pragma("unroll") for (int m = 0; m < 4; m++)                         \
        SET[m] = *(const s16x8*)(apkb + ((size_t)m * CKa + (cc)) * 512);  \
    __builtin_amdgcn_sched_barrier(0);                                    \
  } while (0)

// ---------------- fused MFMA GEMM pair, 4 waves x 64x64 tiles ----------------
// DOWN=0: shared-gu (0..703) + expert-gu (704..2111), nt=64, A via LDS DMA
// DOWN=1: shared-down splitK4 (0..511) + expert-down (512..1535), nt=44,
//         A-frags direct from packed activations (no A LDS)
template <int DOWN>
__global__ void __launch_bounds__(256, 1) k_mm(
    const unsigned short* __restrict__ A_sh, const unsigned short* __restrict__ A_ex,
    const float* __restrict__ B_sh, const float* __restrict__ B_ex,
    unsigned short* __restrict__ act_sh, unsigned short* __restrict__ act_ex,
    float* __restrict__ out,
    const int* __restrict__ counts, const int* __restrict__ tlist,
    const float* __restrict__ wlist, const float* __restrict__ gate_sig) {
  const int tid = threadIdx.x;
  const int lane = tid & 63;
  const int wid = tid >> 6;
  const int wm = wid >> 1, wn = wid & 1;  // 4 waves: 2x2 of 64x64

  constexpr int SHBLK = DOWN ? 512 : 704;
  constexpr int nt = DOWN ? 44 : 64;
  const int b0 = blockIdx.x;
  const bool ex = b0 >= SHBLK;
  const int b = ex ? b0 - SHBLK : b0;
  const int xcd = b & 7;
  const int j = b >> 3;
  const int mtile = j & 7;
  int e = 0, ntile = 0, z = 0;
  if constexpr (!DOWN) {
    if (!ex) ntile = xcd * 11 + (j >> 3);
    else { e = xcd; ntile = j >> 3; }          // e = XCD: A/B panels L2-resident
  } else {
    if (!ex) { int p = xcd * 8 + (j >> 3); ntile = p >> 2; z = p & 3; }
    else { e = xcd; ntile = j >> 3; }
  }

  int lda = 0, ldb, IK = 0, kbeg = 0, count = T_TOK, CKa = 0;
  const unsigned short* A = nullptr;      // gu: linear bf16 rows
  const unsigned short* Apk = nullptr;    // down: packed frags
  const float* Bb0; const float* Bb1;
  const int* tlA = nullptr;
  const int* tlO = nullptr;
  const float* wl = nullptr;
  unsigned short* actout = nullptr;

  if constexpr (!DOWN) {
    lda = H_DIM;
    if (!ex) {
      ldb = 2 * ISD; IK = ISD; A = A_sh; actout = act_sh;
      Bb0 = B_sh + ntile * 64; Bb1 = B_sh + ISD + ntile * 64;
    } else {
      count = counts[e];
      if (mtile * 128 >= count) return;
      ldb = 2 * IED; IK = IED; A = A_sh;
      const float* Bw = B_ex + (size_t)e * H_DIM * (2 * IED);
      Bb0 = Bw + ntile * 64; Bb1 = Bw + IED + ntile * 64;
      tlA = tlist + e * T_TOK; wl = wlist + e * T_TOK;
      actout = act_ex + (size_t)e * T_TOK * IED;
    }
  } else {
    ldb = H_DIM;
    if (!ex) {
      kbeg = z * 1408; Apk = A_sh; CKa = ISD >> 5;   // 176
      Bb0 = B_sh + ntile * 128; Bb1 = Bb0;
    } else {
      count = counts[e];
      if (mtile * 128 >= count) return;
      Apk = A_ex + (size_t)e * T_TOK * IED; CKa = IED >> 5;  // 44
      Bb0 = B_ex + (size_t)e * IED * H_DIM + ntile * 128; Bb1 = Bb0;
      tlO = tlist + e * T_TOK;
    }
  }

  __shared__ unsigned short a_lds[DOWN ? 64 : 2 * 4096];
  __shared__ unsigned short b_lds[2 * 4096];

  // gu A staging (DMA): row = wid*32 + q*16 + (lane>>2), chunkpos = lane&3.
  const unsigned short* asrc[2];
  unsigned short* adst[2];
  if constexpr (!DOWN) {
#pragma unroll
    for (int q = 0; q < 2; q++) {
      int row = wid * 32 + q * 16 + (lane >> 2);
      int rowg = mtile * 128 + row;
      int arow = rowg;
      if (tlA) arow = tlA[rowg];  // padding slots hold 0 (memset)
      asrc[q] = A + (size_t)arow * lda + (((lane & 3) ^ SWZ(row)) * 8);
      adst[q] = &a_lds[(wid * 32 + q * 16) * 32];
    }
  }

  // down A-frag base: g0 = mtile*8 + wm*4; addr(m,c) = ((g0+m)*CKa + c)*512 + lane*8
  const unsigned short* apkb = nullptr;
  if constexpr (DOWN)
    apkb = Apk + (size_t)(mtile * 8 + wm * 4) * CKa * 512 + lane * 8;

  // B staging: col bnn = tid&127, k-half bc = tid>>7.
  const int bnn = tid & 127;
  const int bc = tid >> 7;
  const float* Bh;
  if constexpr (!DOWN) Bh = (bnn < 64) ? (Bb0 + bnn) : (Bb1 + (bnn - 64));
  else Bh = Bb0 + bnn;
  unsigned short* bwr[2];
#pragma unroll
  for (int t = 0; t < 2; t++)
    bwr[t] = &b_lds[bnn * 32 + (((bc * 2 + t) ^ SWZ(bnn)) * 8)];

  const f32x4 fzero = {0.f, 0.f, 0.f, 0.f};
  f32x4 acc[4][4];
#pragma unroll
  for (int m = 0; m < 4; m++)
#pragma unroll
    for (int n = 0; n < 4; n++) acc[m][n] = fzero;

  float RB[16];

  if constexpr (!DOWN) {
    // ---------------- gu: A via LDS DMA, r10-proven ledger ----------------
    ISSUE_AD(kbeg, 0);            // A(0) [2 DMA]
    ISSUE_B(kbeg);                // B(0) [16]
    ISSUE_AD(kbeg + 32, 4096);    // A(1) [2]
    CVTB(0);                      // waits B(0) -> drains A(0); A(1) stays
    ISSUE_B(kbeg + 32);           // B(1) [16]
    __builtin_amdgcn_sched_barrier(0);
    asm volatile("s_waitcnt lgkmcnt(0)" ::: "memory");
    __builtin_amdgcn_s_barrier();
    __builtin_amdgcn_sched_barrier(0);
    // pending: A(1)[2] + B(1)[16]
    for (int u = 0; u < nt; ++u) {
      const int cur = (u & 1) * 4096;
      const int nxt = cur ^ 4096;
      const int k0 = kbeg + u * 32;
      const bool haveN1 = (u + 1 < nt);
      const bool haveN2 = (u + 2 < nt);
      if (haveN1) {
        ISSUE_AD(k0 + 32, nxt);
        CVTB(nxt);                    // B(u+1) regs -> nxt (compiler-counted)
        if (haveN2) ISSUE_B(k0 + 64);
      }
      {  // COMPUTE from LDS A + LDS B
        const unsigned short* ab = a_lds + cur;
        const unsigned short* bb2 = b_lds + cur;
        __builtin_amdgcn_s_setprio(1);
        const int kc = lane >> 4;
        s16x8 am[4];
#pragma unroll
        for (int m = 0; m < 4; m++) {
          int r = wm * 64 + m * 16 + (lane & 15);
          am[m] = *(const s16x8*)&ab[r * 32 + ((kc ^ SWZ(r)) * 8)];
        }
#pragma unroll
        for (int nf = 0; nf < 4; nf++) {
          int rb_ = (nf < 2) ? (wn * 32 + nf * 16) : (64 + wn * 32 + (nf - 2) * 16);
          rb_ += (lane & 15);
          s16x8 bf = *(const s16x8*)&bb2[rb_ * 32 + ((kc ^ SWZ(rb_)) * 8)];
#pragma unroll
          for (int m = 0; m < 4; m++)
            acc[m][nf] = __builtin_amdgcn_mfma_f32_16x16x32_bf16(am[m], bf, acc[m][nf], 0, 0, 0);
        }
        __builtin_amdgcn_s_setprio(0);
      }
      if (haveN1) {
        __builtin_amdgcn_sched_barrier(0);
        if (haveN2)
          asm volatile("s_waitcnt vmcnt(16)" ::: "memory");  // drain A(u+1); keep B(u+2)
        else
          asm volatile("s_waitcnt vmcnt(0)" ::: "memory");
        asm volatile("s_waitcnt lgkmcnt(0)" ::: "memory");
        __builtin_amdgcn_s_barrier();
        __builtin_amdgcn_sched_barrier(0);
      }
    }
    // ---- epilogue: silu(g)*u*rsc -> PACKED activation layout ----
#pragma unroll
    for (int m = 0; m < 4; m++) {
      const int g = mtile * 8 + wm * 4 + m;
#pragma unroll
      for (int i = 0; i < 4; i++) {
        int rowslot = mtile * 128 + wm * 64 + m * 16 + (lane >> 4) * 4 + i;
        float rsc = 1.f;
        if (wl) rsc = wl[rowslot];  // padding slots: 0.0 (memset)
        int l2b = (lane >> 4) * 4 + i + ((lane >> 3) & 1) * 16;
#pragma unroll
        for (int p = 0; p < 2; p++) {
          float gv = acc[m][p][i];
          float uv = acc[m][p + 2][i];
          float sv = gv / (1.f + __expf(-gv)) * uv * rsc;
          size_t addr = ((size_t)(g * (IK >> 5) + ntile * 2 + wn) * 64 + (l2b + p * 32)) * 8 + (lane & 7);
          actout[addr] = f2bf(sv);
        }
      }
    }
  } else {
    // ---------------- down: A-frags direct from packed global ----------------
    s16x8 AF0[4], AF1[4];
    const int c0 = kbeg >> 5;
    ISSUE_AF(AF0, c0);            // AF(0) [4 reg loads]
    ISSUE_B(kbeg);                // B(0) [16]
    CVTB(0);                      // waits B(0)
    ISSUE_B(kbeg + 32);           // B(1) [16]
    __builtin_amdgcn_sched_barrier(0);
    asm volatile("s_waitcnt lgkmcnt(0)" ::: "memory");
    __builtin_amdgcn_s_barrier();
    __builtin_amdgcn_sched_barrier(0);

#define DN_STEP(UU, AFC, AFN)                                             \
    do {                                                                  \
      const int u_ = (UU);                                                \
      const int cur_ = (u_ & 1) * 4096;                                   \
      const bool h1 = (u_ + 1 < nt), h2 = (u_ + 2 < nt);                  \
      if (h1) {                                                           \
        ISSUE_AF(AFN, c0 + u_ + 1);                                       \
        CVTB(cur_ ^ 4096);                                                \
        if (h2) ISSUE_B(kbeg + u_ * 32 + 64);                             \
      }                                                                   \
      {                                                                   \
        const unsigned short* bb2 = b_lds + cur_;                         \
        __builtin_amdgcn_s_setprio(1);                                    \
        const int kc = lane >> 4;                                         \
        _Pragma("unroll") for (int nf = 0; nf < 4; nf++) {                \
          int rb_ = wn * 64 + nf * 16 + (lane & 15);                      \
          s16x8 bf = *(const s16x8*)&bb2[rb_ * 32 + ((kc ^ SWZ(rb_)) * 8)]; \
          _Pragma("unroll") for (int m = 0; m < 4; m++)                   \
              acc[m][nf] = __builtin_amdgcn_mfma_f32_16x16x32_bf16(       \
                  AFC[m], bf, acc[m][nf], 0, 0, 0);                       \
        }                                                                 \
        __builtin_amdgcn_s_setprio(0);                                    \
      }                                                                   \
      if (h1) {                                                           \
        __builtin_amdgcn_sched_barrier(0);                                \
        asm volatile("s_waitcnt lgkmcnt(0)" ::: "memory");                \
        __builtin_amdgcn_s_barrier();                                     \
        __builtin_amdgcn_sched_barrier(0);                                \
      }                                                                   \
    } while (0)

    for (int u = 0; u < nt; u += 2) {
      DN_STEP(u, AF0, AF1);
      DN_STEP(u + 1, AF1, AF0);
    }
#undef DN_STEP

    // ---- epilogue: scatter atomicAdd ----
#pragma unroll
    for (int m = 0; m < 4; m++) {
#pragma unroll
      for (int i = 0; i < 4; i++) {
        int rowslot = mtile * 128 + wm * 64 + m * 16 + (lane >> 4) * 4 + i;
        int token = rowslot;
        if (tlO) token = tlO[rowslot];  // padding: token 0, acc==0
        float sc = ex ? 1.f : gate_sig[token];
        float* orow = out + (size_t)token * H_DIM + ntile * 128 + wn * 64 + (lane & 15);
#pragma unroll
        for (int nf = 0; nf < 4; nf++)
          atomicAdd(orow + nf * 16, acc[m][nf][i] * sc);
      }
    }
  }
}

extern "C" void kernel_launch(void* const* d_in, const int* in_sizes, int n_in,
                              void* d_out, int out_size, void* d_ws, size_t ws_size,
                              hipStream_t stream) {
  (void)in_sizes; (void)n_in; (void)out_size; (void)ws_size;
  const float* x    = (const float*)d_in[0];
  const float* wg   = (const float*)d_in[1];
  const float* wsg  = (const float*)d_in[2];
  const float* wsgu = (const float*)d_in[3];
  const float* wsd  = (const float*)d_in[4];
  const float* wegu = (const float*)d_in[5];
  const float* wed  = (const float*)d_in[6];
  float* out = (float*)d_out;

  char* ws = (char*)d_ws;
  unsigned short* xb   = (unsigned short*)ws;                                   // 4 MB
  unsigned short* acts = (unsigned short*)(ws + (4u << 20));                    // packed, T*ISD bf16
  unsigned short* acte = (unsigned short*)(ws + (4u << 20) + 11534336u);        // packed, E*T*IED bf16
  char* ctrl = ws + (4u << 20) + 11534336u + 23068672u;
  int* counts    = (int*)ctrl;
  int* tlist     = (int*)(ctrl + 256);
  float* wlist   = (float*)(ctrl + 256 + 32768);
  float* gate_sig = (float*)(ctrl + 256 + 65536);

  hipMemsetAsync(d_out, 0, (size_t)T_TOK * H_DIM * 4, stream);
  hipMemsetAsync(ctrl, 0, 256 + 65536, stream);

  k_router<<<dim3(256), dim3(256), 0, stream>>>(x, wg, wsg, xb, counts, tlist, wlist, gate_sig);
  k_mm<0><<<dim3(2112), dim3(256), 0, stream>>>(xb, xb, wsgu, wegu, acts, acte, nullptr,
                                                counts, tlist, wlist, gate_sig);
  k_mm<1><<<dim3(1536), dim3(256), 0, stream>>>(acts, acte, wsd, wed, nullptr, nullptr, out,
                                                counts, tlist, wlist, gate_sig);
}